// Round 10
// baseline (187.110 us; speedup 1.0000x reference)
//
#include <hip/hip_runtime.h>

#define LAMC    10000.0f
#define INV_LAM 1e-4f
#define EPSC    1e-12f
#define TOLC    1e-6f
#define BLK     256
#define WPB     (BLK / 64)       // waves per block
#define PPT     2                // pairs per thread
#define PRW     128              // pairs per wave (64 lanes x PPT)

__device__ __forceinline__ float frcp(float x)  { return __builtin_amdgcn_rcpf(x); }
__device__ __forceinline__ float frsq(float x)  { return __builtin_amdgcn_rsqf(x); }
__device__ __forceinline__ float fsqrt_(float x){ return __builtin_amdgcn_sqrtf(x); }

// sign(phi(t)) without sqrt/div: phi = L - R*sqrt(q), q >= EPS > 0
__device__ __forceinline__ bool phi_pos(float t, float A, float p, float N, float b) {
    float q  = fmaxf(fmaf(t, fmaf(t, A, -2.0f * p), N), EPSC);
    float L  = fmaf(-t, A, p);        // p - t*A   (U_MAX = 1)
    float R  = fmaf(t, INV_LAM, b);   // b + t/LAM
    float L2 = L * L;
    float Rq = (R * R) * q;
    return (R < 0.0f) ? ((L >= 0.0f) || (L2 < Rq))
                      : ((L >  0.0f) && (L2 > Rq));
}

// 2 independent heavy rows, interleaved chains (R7-verified algorithm):
//  bracket rows: 8 geometric bisections + 5 safeguarded clamped Newtons;
//  collapse rows (phi(0)<=0): 3 unclamped Newtons from 0, frozen after.
__device__ __forceinline__ void heavy_solve2(const float ux[2], const float uy[2],
                                             const float ax[2], const float ay[2],
                                             const float bb[2], float2 res[2]) {
    float A[2], p[2], N[2], t3[2], lo[2], hi[2];
    bool  br[2];
    #pragma unroll
    for (int r = 0; r < 2; ++r) {
        A[r] = fmaf(ax[r], ax[r], ay[r] * ay[r]);
        p[r] = fmaf(ax[r], ux[r], ay[r] * uy[r]);
        N[r] = fmaf(ux[r], ux[r], uy[r] * uy[r]);
        br[r] = phi_pos(0.0f, A[r], p[r], N[r], bb[r]);
        float tA = p[r] * frcp(fmaxf(A[r], 1e-30f));
        bool hiTA = (p[r] > 0.0f) && (fmaf(tA, INV_LAM, bb[r]) >= 0.0f);
        bool loTA = (p[r] > 0.0f) && !hiTA;
        float l = loTA ? tA : 0.0f;
        float h = hiTA ? tA : -LAMC * bb[r];
        lo[r] = br[r] ? l : 0.0f;
        hi[r] = br[r] ? h : 0.0f;
        t3[r] = 0.0f;
    }
    #pragma unroll 1
    for (int k = 0; k < 8; ++k) {            // geometric bisection, 2-way ILP
        #pragma unroll
        for (int r = 0; r < 2; ++r) {
            float fl  = fmaxf(lo[r], 1e-6f * hi[r]);
            float mid = fsqrt_(fl * hi[r]);
            bool pos  = phi_pos(mid, A[r], p[r], N[r], bb[r]);
            lo[r] = pos ? mid : lo[r];
            hi[r] = pos ? hi[r] : mid;
        }
    }
    #pragma unroll
    for (int r = 0; r < 2; ++r) t3[r] = br[r] ? 0.5f * (lo[r] + hi[r]) : 0.0f;
    #pragma unroll 1
    for (int it = 0; it < 5; ++it) {         // Newton, 2-way ILP
        #pragma unroll
        for (int r = 0; r < 2; ++r) {
            float q   = fmaxf(fmaf(t3[r], fmaf(t3[r], A[r], -2.0f * p[r]), N[r]), EPSC);
            float nrm = fsqrt_(q);
            float R   = fmaf(t3[r], INV_LAM, bb[r]);
            float f   = fmaf(-t3[r], A[r], p[r]) - R * nrm;
            float df  = -A[r] - nrm * INV_LAM - R * fmaf(t3[r], A[r], -p[r]) * frcp(nrm);
            df = (fabsf(df) > 1e-8f) ? df : -1e-8f;
            bool fp = f > 0.0f;              // phi(t3)>0 -> root above t3
            lo[r] = (br[r] && fp)  ? t3[r] : lo[r];
            hi[r] = (br[r] && !fp) ? t3[r] : hi[r];
            float tn   = t3[r] - f * frcp(df);
            float tb   = fminf(fmaxf(tn, lo[r]), hi[r]);
            float tupd = br[r] ? tb : tn;    // collapse rows: unclamped
            t3[r] = (!br[r] && it >= 3) ? t3[r] : tupd;  // freeze collapse after 3
        }
    }
    #pragma unroll
    for (int r = 0; r < 2; ++r) {
        float q3  = fmaxf(fmaf(t3[r], fmaf(t3[r], A[r], -2.0f * p[r]), N[r]), EPSC);
        float k3  = fmaxf(fsqrt_(q3), 1.0f);
        float inv = frcp(k3);
        res[r] = make_float2(fmaf(-t3[r], ax[r], ux[r]) * inv,
                             fmaf(-t3[r], ay[r], uy[r]) * inv);
    }
}

// branchless easy path; a,b precomputed. returns true if heavy (branch 3).
__device__ __forceinline__ bool easy_row(float ux, float uy,
                                         float ax, float ay, float b,
                                         float& ox, float& oy) {
    float A  = fmaf(ax, ax, ay * ay);
    float p  = fmaf(ax, ux, ay * uy);
    float N  = fmaf(ux, ux, uy * uy);
    float s1 = fminf(1.0f, frsq(fmaxf(N, EPSC)));   // min(1, 1/|u|)
    float u1x = ux * s1, u1y = uy * s1;
    bool feas1 = fmaf(ax, u1x, ay * u1y) <= b + TOLC;
    float t2  = LAMC * (p - b) * frcp(fmaf(LAMC, A, 1.0f));
    float u2x = fmaf(-t2, ax, ux), u2y = fmaf(-t2, ay, uy);
    bool ok2 = (t2 >= -TOLC) && (fmaf(u2x, u2x, u2y * u2y) <= 1.0f + TOLC);
    ox = feas1 ? u1x : u2x;
    oy = feas1 ? u1y : u2y;
    return !feas1 && !ok2;
}

__global__ __launch_bounds__(BLK) void cbf_kernel(const float4* __restrict__ u4,
                                                  const float4* __restrict__ obs4,
                                                  float4* __restrict__ out4,
                                                  int npair) {
    // per-wave 6KB obs chunk (identity copy via registers, fully coalesced:
    // lane-striped contiguous float4 -> 4 lanes per 64B line, merged requests).
    // After consumption, start is reused as solver staging: sdat[256] + sbv[256].
    __shared__ float4 obsbuf[WPB][3 * PRW];   // 24 KB total

    int tid  = threadIdx.x;
    int wave = tid >> 6;
    int lane = tid & 63;
    unsigned long long ltmask = (1ull << lane) - 1ull;
    int wpb = blockIdx.x * (BLK * PPT) + wave * PRW;   // wave's first pair

    float4* sdat = &obsbuf[wave][0];
    float*  sbv  = (float*)&obsbuf[wave][256];

    int  i0 = wpb + lane, i1 = wpb + 64 + lane;
    bool v0 = i0 < npair, v1 = i1 < npair;
    float4 z = make_float4(0.f, 0.f, 0.f, 0.f);
    float4 ua = v0 ? u4[i0] : z;              // contiguous, coalesced
    float4 ub = v1 ? u4[i1] : z;

    // ---- phase 1: contiguous lane-striped copy of wave's obs chunk to LDS
    {
        const float4* src = obs4 + 3 * (size_t)wpb;
        long nf4 = 3 * ((long)npair - (long)wpb);          // valid float4s in chunk
        float4 tmp[6];
        #pragma unroll
        for (int c = 0; c < 6; ++c) {                      // issue all loads first
            int idx = c * 64 + lane;
            tmp[c] = (idx < nf4) ? src[idx] : z;
        }
        #pragma unroll
        for (int c = 0; c < 6; ++c)
            obsbuf[wave][c * 64 + lane] = tmp[c];
    }

    // ---- phase 2: pick apart rows from LDS, compute easy paths
    float4 o[2][3];
    #pragma unroll
    for (int k = 0; k < 2; ++k)
        #pragma unroll
        for (int c = 0; c < 3; ++c)
            o[k][c] = obsbuf[wave][3 * (k * 64 + lane) + c];

    float4 r0 = z, r1 = z;
    bool hv[4];
    float sx[4], sy[4], sax[4], say[4], sb[4];
    {
        float4 uu = ua;
        float ax0 = -2.0f * o[0][0].z, ay0 = -2.0f * o[0][0].w;
        float b0  = fmaf(2.0f, fmaf(o[0][0].z, o[0][0].z, o[0][0].w * o[0][0].w) - 1.0f,
                         -2.0f * fmaf(o[0][0].z, o[0][1].x, o[0][0].w * o[0][1].y));
        float ax1 = -2.0f * o[0][2].x, ay1 = -2.0f * o[0][2].y;
        float b1  = fmaf(2.0f, fmaf(o[0][2].x, o[0][2].x, o[0][2].y * o[0][2].y) - 1.0f,
                         -2.0f * fmaf(o[0][2].x, o[0][2].z, o[0][2].y * o[0][2].w));
        hv[0] = v0 && easy_row(uu.x, uu.y, ax0, ay0, b0, r0.x, r0.y);
        hv[1] = v0 && easy_row(uu.z, uu.w, ax1, ay1, b1, r0.z, r0.w);
        sx[0] = uu.x; sy[0] = uu.y; sax[0] = ax0; say[0] = ay0; sb[0] = b0;
        sx[1] = uu.z; sy[1] = uu.w; sax[1] = ax1; say[1] = ay1; sb[1] = b1;
    }
    {
        float4 uu = ub;
        float ax0 = -2.0f * o[1][0].z, ay0 = -2.0f * o[1][0].w;
        float b0  = fmaf(2.0f, fmaf(o[1][0].z, o[1][0].z, o[1][0].w * o[1][0].w) - 1.0f,
                         -2.0f * fmaf(o[1][0].z, o[1][1].x, o[1][0].w * o[1][1].y));
        float ax1 = -2.0f * o[1][2].x, ay1 = -2.0f * o[1][2].y;
        float b1  = fmaf(2.0f, fmaf(o[1][2].x, o[1][2].x, o[1][2].y * o[1][2].y) - 1.0f,
                         -2.0f * fmaf(o[1][2].x, o[1][2].z, o[1][2].y * o[1][2].w));
        hv[2] = v1 && easy_row(uu.x, uu.y, ax0, ay0, b0, r1.x, r1.y);
        hv[3] = v1 && easy_row(uu.z, uu.w, ax1, ay1, b1, r1.z, r1.w);
        sx[2] = uu.x; sy[2] = uu.y; sax[2] = ax0; say[2] = ay0; sb[2] = b0;
        sx[3] = uu.z; sy[3] = uu.w; sax[3] = ax1; say[3] = ay1; sb[3] = b1;
    }

    // all phase-2 LDS reads must land before compaction overwrites the buffer
    // (per-wave LDS ops are in-order; asm fence stops compiler reordering)
    asm volatile("s_waitcnt lgkmcnt(0)" ::: "memory");

    // ---- phase 3: wave-local ballot compaction into aliased staging
    int tot = 0;
    int slot[4];
    #pragma unroll
    for (int m = 0; m < 4; ++m) {
        unsigned long long mm = __ballot(hv[m]);
        slot[m] = tot + __popcll(mm & ltmask);
        if (hv[m]) {
            sdat[slot[m]] = make_float4(sx[m], sy[m], sax[m], say[m]);
            sbv [slot[m]] = sb[m];
        }
        tot += __popcll(mm);
    }
    __threadfence_block();   // wave lockstep + lgkmcnt drain orders LDS w->r

    // ---- phase 4: heavy batches, 2 rows/lane, results written in place
    #pragma unroll 1
    for (int base = 0; base < tot; base += 128) {
        float hux[2], huy[2], hax[2], hay[2], hbb[2];
        float2 hres[2];
        int jj[2];
        #pragma unroll
        for (int q = 0; q < 2; ++q) {
            int j  = base + q * 64 + lane;
            jj[q]  = j;
            int js = (j < tot) ? j : (tot - 1);   // clamp: duplicate work, no store
            float4 d = sdat[js];
            hux[q] = d.x;  huy[q] = d.y;  hax[q] = d.z;  hay[q] = d.w;
            hbb[q] = sbv[js];
        }
        heavy_solve2(hux, huy, hax, hay, hbb, hres);
        #pragma unroll
        for (int q = 0; q < 2; ++q)
            if (jj[q] < tot) *(float2*)&sdat[jj[q]] = hres[q];
    }
    __threadfence_block();

    if (hv[0]) { float2 s = *(const float2*)&sdat[slot[0]]; r0.x = s.x; r0.y = s.y; }
    if (hv[1]) { float2 s = *(const float2*)&sdat[slot[1]]; r0.z = s.x; r0.w = s.y; }
    if (hv[2]) { float2 s = *(const float2*)&sdat[slot[2]]; r1.x = s.x; r1.y = s.y; }
    if (hv[3]) { float2 s = *(const float2*)&sdat[slot[3]]; r1.z = s.x; r1.w = s.y; }

    if (v0) out4[i0] = r0;                    // contiguous, coalesced
    if (v1) out4[i1] = r1;
}

extern "C" void kernel_launch(void* const* d_in, const int* in_sizes, int n_in,
                              void* d_out, int out_size, void* d_ws, size_t ws_size,
                              hipStream_t stream) {
    const float* u_nom = (const float*)d_in[0];
    const float* obs   = (const float*)d_in[1];
    float* out = (float*)d_out;
    int rows   = in_sizes[0] / 2;             // B
    int npair  = rows / 2;                    // 2 rows per thread-slot
    int blocks = (npair + BLK * PPT - 1) / (BLK * PPT);
    cbf_kernel<<<blocks, BLK, 0, stream>>>((const float4*)u_nom,
                                           (const float4*)obs,
                                           (float4*)out, npair);
}